// Round 6
// baseline (1781.037 us; speedup 1.0000x reference)
//
#include <hip/hip_runtime.h>
#include <hip/hip_cooperative_groups.h>
#include <math.h>

namespace cg = cooperative_groups;

// Problem constants (fixed by setup_inputs): B=8 graphs, N=50000 nodes/graph,
// EPG=1e6 edges/graph, E=8e6, M=2048, num_passes=3.
#define GB    8
#define GN    50000
#define EPG   1000000
#define EDGES (GB*EPG)
#define NP    3

#define BW     4096           // dst-bucket width (floats) -> 16KB LDS accum
#define NBUCK  13             // ceil(50000/4096); last bucket width 848
#define NBINS  (GB*NBUCK)     // 104
#define CAP    89088          // fixed recs capacity per bin (mean 81920, +26σ)
#define CPB    19             // chunk-blocks per bin -> 1976 accum blocks
#define GRID   (CPB*NBINS)    // 1976 fused-kernel blocks (< 2048 co-resident cap)
#define STRIPE 5000           // edges per binning stripe
#define NQ     (STRIPE/4)     // 1250 quads
#define NU     5              // ceil(NQ/256)
#define NBLKH  (EDGES/STRIPE) // 1600 stripes (each handled by one block)
#define BPG    (EPG/STRIPE)   // 200 stripes per graph
#define SRCMASK 0x7FFFFu      // src fits 19 bits (BN=400000 < 2^19)

// ============================ fast path ============================
// Round-5 ledger: dispatch-sum ~281us vs wall 362us => ~80us of inter-
// dispatch launch/drain overhead across 8 dependent kernels. Round 6 fuses
// the whole pipeline into ONE cooperative kernel (grid.sync between phases),
// sized for guaranteed co-residency (1976 blocks, 256 thr, <=64 VGPR via
// __launch_bounds__(256,8), 16.5KB LDS -> 8 blocks/CU wave-capped).
// Phase bodies are the PROVEN round-5 kernels verbatim (device functions).
// Fallback 1: coop launch fails -> round-5 multi-kernel path (no regression).
// Fallback 2: shapes mismatch -> v1 atomic path.

// ---- phase bodies (shared by fused + standalone kernels) ----

// Fused bin+rank+reserve+scatter (proven 62us structure; dst-binned):
//  rec.x = (dst_in_bucket << 19) | src_global, rec.y = bits(log1pf(w))
// After completion, gcur[bin] == bin's record count.
__device__ __forceinline__ void dev_fscatter(
    const int* __restrict__ src, const int* __restrict__ dst,
    const float* __restrict__ ew, int* __restrict__ gcur,
    uint2* __restrict__ recs, int blk, int* lh, int* lb) {
  if (threadIdx.x < NBINS) lh[threadIdx.x] = 0;
  __syncthreads();
  int s0 = blk * STRIPE;
  int g = blk / BPG;                  // stripe never crosses a graph
  int base = g * GN, gb = g * NBUCK;
  const int4* d4 = (const int4*)(dst + s0);
  const int4* s4 = (const int4*)(src + s0);
  const float4* w4 = (const float4*)(ew + s0);

  int rk[4 * NU];
#pragma unroll
  for (int u = 0; u < NU; ++u) {
    int q = threadIdx.x + 256 * u;
    if (q < NQ) {
      int4 d = d4[q];
      rk[4 * u + 0] = atomicAdd(&lh[gb + ((d.x - base) >> 12)], 1);
      rk[4 * u + 1] = atomicAdd(&lh[gb + ((d.y - base) >> 12)], 1);
      rk[4 * u + 2] = atomicAdd(&lh[gb + ((d.z - base) >> 12)], 1);
      rk[4 * u + 3] = atomicAdd(&lh[gb + ((d.w - base) >> 12)], 1);
    }
  }
  __syncthreads();
  if (threadIdx.x < NBINS) {
    int c = lh[threadIdx.x];
    lb[threadIdx.x] = c ? atomicAdd(&gcur[threadIdx.x], c) : 0;
  }
  __syncthreads();
#pragma unroll
  for (int u = 0; u < NU; ++u) {
    int q = threadIdx.x + 256 * u;
    if (q < NQ) {
      int4 d = d4[q]; int4 s = s4[q]; float4 w = w4[q];
      int dv[4] = {d.x, d.y, d.z, d.w};
      int sv[4] = {s.x, s.y, s.z, s.w};
      float wv[4] = {w.x, w.y, w.z, w.w};
#pragma unroll
      for (int k = 0; k < 4; ++k) {
        int dl = dv[k] - base;
        int bin = gb + (dl >> 12);
        int r = dl & (BW - 1);
        size_t pos = (size_t)bin * CAP + lb[bin] + rk[4 * u + k];
        recs[pos] = make_uint2(((unsigned)r << 19) | (unsigned)sv[k],
                               __float_as_uint(log1pf(wv[k])));
      }
    }
  }
}

// One (bin, chunk): LDS-accumulate this bin's edges; 2x uint4/iter; zero-skip
// coalesced atomic epilogue into hout (pre-zeroed). Proven round-5 body.
__device__ __forceinline__ void dev_accum(
    const uint2* __restrict__ recs, const int* __restrict__ cnt,
    const float* __restrict__ hin, float* __restrict__ hout,
    int c, int bin, float* acc) {
  float4 z = {0.f, 0.f, 0.f, 0.f};
  float4* a4 = (float4*)acc;
  for (int i = threadIdx.x; i < BW / 4; i += 256) a4[i] = z;
  int len = cnt[bin];
  int chunk = ((len + CPB - 1) / CPB + 1) & ~1;   // even chunk
  int lo = c * chunk;
  int hi = lo + chunk;
  if (lo > len) lo = len;
  if (hi > len) hi = len;
  const uint2* rb = recs + (size_t)bin * CAP;
  __syncthreads();
  int rem = hi - lo;                // lo even (CAP even, chunk even)
  if (rem < 0) rem = 0;
  int np = rem >> 1;                // uint4 count (2 recs each)
  const uint4* rp = (const uint4*)(rb + lo);
  int p = threadIdx.x;
  for (; p + 256 < np; p += 512) {
    uint4 r0 = rp[p];
    uint4 r1 = rp[p + 256];
    float a0 = hin[r0.x & SRCMASK] * __uint_as_float(r0.y);
    float a1 = hin[r0.z & SRCMASK] * __uint_as_float(r0.w);
    float a2 = hin[r1.x & SRCMASK] * __uint_as_float(r1.y);
    float a3 = hin[r1.z & SRCMASK] * __uint_as_float(r1.w);
    atomicAdd(&acc[r0.x >> 19], a0);
    atomicAdd(&acc[r0.z >> 19], a1);
    atomicAdd(&acc[r1.x >> 19], a2);
    atomicAdd(&acc[r1.z >> 19], a3);
  }
  if (p < np) {
    uint4 r0 = rp[p];
    atomicAdd(&acc[r0.x >> 19], hin[r0.x & SRCMASK] * __uint_as_float(r0.y));
    atomicAdd(&acc[r0.z >> 19], hin[r0.z & SRCMASK] * __uint_as_float(r0.w));
  }
  if ((rem & 1) && threadIdx.x == 0) {
    uint2 a = rb[hi - 1];
    atomicAdd(&acc[a.x >> 19], hin[a.x & SRCMASK] * __uint_as_float(a.y));
  }
  __syncthreads();
  int g = bin / NBUCK, bucket = bin - g * NBUCK;
  int sw = GN - bucket * BW; if (sw > BW) sw = BW;   // 848 for bucket 12
  float* ho = hout + (size_t)g * GN + (size_t)bucket * BW;
  for (int i = threadIdx.x; i < sw; i += 256) {
    float v = acc[i];
    if (v != 0.f) unsafeAtomicAdd(&ho[i], v);
  }
}

__device__ __forceinline__ float blk_red(float t, float* sm, int nw) {
  for (int o = 32; o > 0; o >>= 1) t += __shfl_down(t, o, 64);
  if ((threadIdx.x & 63) == 0) sm[threadIdx.x >> 6] = t;
  __syncthreads();
  float r = 0.f;
  for (int w = 0; w < nw; ++w) r += sm[w];
  __syncthreads();
  return r;
}

// Telescoped norm + mask/normalize/pool epilogue (proven round-5 body).
__device__ __forceinline__ void dev_final(
    const float* __restrict__ h, const float* __restrict__ nsq,
    const int* __restrict__ dm, const float* __restrict__ fc_w,
    const float* __restrict__ fc_b, float* __restrict__ out,
    int b, int N, int M, float* v, float* sm) {
  int nw = blockDim.x >> 6;
  float inv = nsq ? 1.0f / sqrtf(nsq[b]) : 1.0f;
  const float* hb = h + (size_t)b * N;
  for (int m = threadIdx.x; m < M; m += blockDim.x) v[m] = hb[dm[m]] * inv;
  __syncthreads();

  float cnt = 0.f, sum = 0.f;
  for (int m = threadIdx.x; m < M; m += blockDim.x) {
    float xv = v[m];
    if (xv != 0.f) { cnt += 1.f; sum += xv; }
  }
  float totalSum = blk_red(sum, sm, nw);
  float totalCnt = blk_red(cnt, sm, nw);
  float mean = totalCnt > 0.f ? totalSum / totalCnt : 0.f;

  float ssq = 0.f;
  for (int m = threadIdx.x; m < M; m += blockDim.x) {
    float xv = v[m];
    if (xv != 0.f) { float d = xv - mean; ssq += d * d; }
  }
  float totalSsq = blk_red(ssq, sm, nw);

  float denom = totalCnt - 1.f;
  if (denom < 1.f) denom = 1.f;
  float stdv = sqrtf(totalSsq / denom) + 1e-5f;

  float ps = 0.f;
  for (int m = threadIdx.x; m < M; m += blockDim.x) {
    float xv = v[m];
    if (xv != 0.f) ps += (xv - mean) / stdv;
  }
  float pooled = blk_red(ps, sm, nw) / (float)M;
  if (threadIdx.x == 0) {
    float o = pooled * fc_w[0] + fc_b[0];
    out[b] = o > 0.f ? o : 0.f;
  }
}

// ---- fused cooperative kernel: one dispatch, 6 grid syncs ----
__global__ __launch_bounds__(256, 8) void fused_k(
    const float* __restrict__ x, const float* __restrict__ ew,
    const int* __restrict__ src, const int* __restrict__ dst,
    const int* __restrict__ dm, const float* __restrict__ fc_w,
    const float* __restrict__ fc_b, float* __restrict__ out,
    uint2* __restrict__ recs, float* __restrict__ bufA,
    float* __restrict__ bufB, float* __restrict__ bufC,
    int* __restrict__ gcur, float* __restrict__ nsq) {
  cg::grid_group grid = cg::this_grid();
  __shared__ float acc[BW];       // reused: lh/lb (fscatter), acc, v (final)
  __shared__ float smr[16];
  __shared__ float smn[GB];
  const int bid = blockIdx.x;
  const int tid = threadIdx.x;

  // phase 0: zero h-buffers + gcur + nsq
  {
    float4 zz = {0.f, 0.f, 0.f, 0.f};
    for (int i = bid * 256 + tid; i < (GB * GN) / 4; i += GRID * 256) {
      ((float4*)bufA)[i] = zz;
      ((float4*)bufB)[i] = zz;
      ((float4*)bufC)[i] = zz;
    }
    if (bid == 0) {
      if (tid < NBINS) gcur[tid] = 0;
      if (tid < GB) nsq[tid] = 0.f;
    }
  }
  grid.sync();

  // phase 1: fscatter (one stripe per block; 1600 of 1976 blocks active)
  if (bid < NBLKH)
    dev_fscatter(src, dst, ew, gcur, recs, bid, (int*)acc, (int*)acc + NBINS);
  grid.sync();

  // phases 2-4: three message-passing rounds (norms telescope)
  {
    int bin = bid / CPB, c = bid - bin * CPB;   // GRID == CPB*NBINS exactly
    dev_accum(recs, gcur, x, bufA, c, bin, acc);
    grid.sync();
    dev_accum(recs, gcur, bufA, bufB, c, bin, acc);
    grid.sync();
    dev_accum(recs, gcur, bufB, bufC, c, bin, acc);
    grid.sync();
  }

  // phase 5: per-graph sum of squares of bufC
  {
    if (tid < GB) smn[tid] = 0.f;
    __syncthreads();
    for (int i = bid * 256 + tid; i < (GB * GN) / 4; i += GRID * 256) {
      float4 t = ((const float4*)bufC)[i];
      int g = (i * 4) / GN;
      atomicAdd(&smn[g], t.x * t.x + t.y * t.y + t.z * t.z + t.w * t.w);
    }
    __syncthreads();
    if (tid < GB && smn[tid] != 0.f) unsafeAtomicAdd(&nsq[tid], smn[tid]);
  }
  grid.sync();

  // phase 6: epilogue (blocks 0..7)
  if (bid < GB)
    dev_final(bufC, nsq, dm, fc_w, fc_b, out, bid, GN, 2048, acc, smr);
}

// ---- standalone kernels (fallback path if coop launch fails) ----

__global__ void z_k(int* __restrict__ gcur, float* __restrict__ nsq,
                    float4* __restrict__ a, float4* __restrict__ b,
                    float4* __restrict__ c) {
  int i = blockIdx.x * 256 + threadIdx.x;
  float4 z = {0.f, 0.f, 0.f, 0.f};
  if (i < (GB * GN) / 4) { a[i] = z; b[i] = z; c[i] = z; }
  if (blockIdx.x == 0) {
    if (threadIdx.x < NBINS) gcur[threadIdx.x] = 0;
    if (threadIdx.x < GB) nsq[threadIdx.x] = 0.f;
  }
}

__global__ __launch_bounds__(256) void fscatter_k(
    const int* __restrict__ src, const int* __restrict__ dst,
    const float* __restrict__ ew, int* __restrict__ gcur,
    uint2* __restrict__ recs) {
  __shared__ int lh[NBINS];
  __shared__ int lb[NBINS];
  dev_fscatter(src, dst, ew, gcur, recs, blockIdx.x, lh, lb);
}

__global__ __launch_bounds__(256) void accum_k(
    const uint2* __restrict__ recs, const int* __restrict__ cnt,
    const float* __restrict__ hin, float* __restrict__ hout) {
  __shared__ float acc[BW];
  dev_accum(recs, cnt, hin, hout, blockIdx.x, blockIdx.y, acc);
}

__global__ void nsq_k(const float4* __restrict__ h4, float* __restrict__ nsq) {
  __shared__ float sm[GB];
  if (threadIdx.x < GB) sm[threadIdx.x] = 0.f;
  __syncthreads();
  int n4 = blockIdx.x * 256 + threadIdx.x;
  if (n4 < (GB * GN) / 4) {
    float4 t = h4[n4];
    int g = (n4 * 4) / GN;
    atomicAdd(&sm[g], t.x * t.x + t.y * t.y + t.z * t.z + t.w * t.w);
  }
  __syncthreads();
  if (threadIdx.x < GB && sm[threadIdx.x] != 0.f)
    unsafeAtomicAdd(&nsq[threadIdx.x], sm[threadIdx.x]);
}

__global__ void final_k(const float* __restrict__ h, const float* __restrict__ nsq,
                        const int* __restrict__ dm,
                        const float* __restrict__ fc_w, const float* __restrict__ fc_b,
                        float* __restrict__ out, int N, int M) {
  extern __shared__ float v[];
  __shared__ float sm[16];
  dev_final(h, nsq, dm, fc_w, fc_b, out, blockIdx.x, N, M, v, sm);
}

// ============================ v1 fallback ============================

__global__ void init_k(const float* __restrict__ x, float* __restrict__ h_cur,
                       float* __restrict__ h_next, float* __restrict__ norms,
                       int BN, int n_norms) {
  int i = blockIdx.x * blockDim.x + threadIdx.x;
  int stride = gridDim.x * blockDim.x;
  for (int j = i; j < BN; j += stride) { h_cur[j] = x[j]; h_next[j] = 0.f; }
  if (i < n_norms) norms[i] = 0.f;
}

__global__ void edge_k(const int* __restrict__ src, const int* __restrict__ dst,
                       const float* __restrict__ ew, const float* __restrict__ h_in,
                       float* __restrict__ h_out, int E4, int E) {
  int i = blockIdx.x * blockDim.x + threadIdx.x;
  int stride = gridDim.x * blockDim.x;
  const int4* s4 = (const int4*)src;
  const int4* d4 = (const int4*)dst;
  const float4* w4 = (const float4*)ew;
  for (int j = i; j < E4; j += stride) {
    int4 s = s4[j]; int4 d = d4[j]; float4 w = w4[j];
    unsafeAtomicAdd(&h_out[d.x], h_in[s.x] * log1pf(w.x));
    unsafeAtomicAdd(&h_out[d.y], h_in[s.y] * log1pf(w.y));
    unsafeAtomicAdd(&h_out[d.z], h_in[s.z] * log1pf(w.z));
    unsafeAtomicAdd(&h_out[d.w], h_in[s.w] * log1pf(w.w));
  }
  for (int j = E4 * 4 + i; j < E; j += stride)
    unsafeAtomicAdd(&h_out[dst[j]], h_in[src[j]] * log1pf(ew[j]));
}

__global__ void norm_k(const float* __restrict__ h, float* __restrict__ norms, int N) {
  int g = blockIdx.y;
  const float* hg = h + (size_t)g * N;
  float s = 0.f;
  for (int j = blockIdx.x * blockDim.x + threadIdx.x; j < N; j += gridDim.x * blockDim.x) {
    float v = hg[j]; s += v * v;
  }
  __shared__ float sm[4];
  for (int o = 32; o > 0; o >>= 1) s += __shfl_down(s, o, 64);
  if ((threadIdx.x & 63) == 0) sm[threadIdx.x >> 6] = s;
  __syncthreads();
  if (threadIdx.x == 0) {
    float t = 0.f;
    for (int w = 0; w < (int)(blockDim.x >> 6); ++w) t += sm[w];
    unsafeAtomicAdd(&norms[g], t);
  }
}

__global__ void scale_k(const float* __restrict__ norms, float* __restrict__ h_next,
                        float* __restrict__ h_cur, int N) {
  int g = blockIdx.y;
  float inv = 1.0f / sqrtf(norms[g]);
  size_t off = (size_t)g * N;
  for (int j = blockIdx.x * blockDim.x + threadIdx.x; j < N; j += gridDim.x * blockDim.x) {
    h_cur[off + j] = h_next[off + j] * inv;
    h_next[off + j] = 0.f;
  }
}

extern "C" void kernel_launch(void* const* d_in, const int* in_sizes, int n_in,
                              void* d_out, int out_size, void* d_ws, size_t ws_size,
                              hipStream_t stream) {
  const float* x    = (const float*)d_in[0];
  const float* ew   = (const float*)d_in[1];
  const int*   src  = (const int*)d_in[2];
  const int*   dst  = (const int*)d_in[3];
  const int*   dm   = (const int*)d_in[4];
  const float* fc_w = (const float*)d_in[5];
  const float* fc_b = (const float*)d_in[6];

  const int BN = in_sizes[0];   // 400000
  const int E  = in_sizes[1];   // 8000000
  const int M  = in_sizes[4];   // 2048
  const int N  = BN / GB;

  const bool shapes_ok = (BN == GB * GN) && (E == EDGES) && (M == 2048);

  // ---- layout (fixed-capacity recs; REQ ~ 79 MB <= verified floor) ----
  const size_t recs_b = (size_t)NBINS * CAP * 8;   // 74,121,216
  const size_t buf_b  = (size_t)BN * 4;            // 1,600,000
  const size_t misc_b = 4096;
  const size_t REQ = recs_b + 3 * buf_b + misc_b;

  if (shapes_ok && ws_size >= REQ) {
    uint2* recs = (uint2*)d_ws;
    float* bufA = (float*)((char*)d_ws + recs_b);
    float* bufB = bufA + BN;
    float* bufC = bufB + BN;
    int*   gcur = (int*)(bufC + BN);               // [NBINS]
    float* nsq  = (float*)(gcur + NBINS + 8);      // [GB]
    float* outp = (float*)d_out;

    // ---- try the single fused cooperative dispatch ----
    void* kargs[] = {
      (void*)&x, (void*)&ew, (void*)&src, (void*)&dst, (void*)&dm,
      (void*)&fc_w, (void*)&fc_b, (void*)&outp,
      (void*)&recs, (void*)&bufA, (void*)&bufB, (void*)&bufC,
      (void*)&gcur, (void*)&nsq
    };
    hipError_t cerr = hipLaunchCooperativeKernel(
        (const void*)fused_k, dim3(GRID), dim3(256), kargs, 0, stream);
    if (cerr == hipSuccess) return;
    (void)hipGetLastError();   // clear error state; fall back

    // ---- proven round-5 multi-kernel path ----
    z_k<<<(BN / 4 + 255) / 256, 256, 0, stream>>>(gcur, nsq, (float4*)bufA,
                                                  (float4*)bufB, (float4*)bufC);
    fscatter_k<<<NBLKH, 256, 0, stream>>>(src, dst, ew, gcur, recs);

    dim3 agrid(CPB, NBINS);
    accum_k<<<agrid, 256, 0, stream>>>(recs, gcur, x, bufA);
    accum_k<<<agrid, 256, 0, stream>>>(recs, gcur, bufA, bufB);
    accum_k<<<agrid, 256, 0, stream>>>(recs, gcur, bufB, bufC);

    nsq_k<<<(BN / 4 + 255) / 256, 256, 0, stream>>>((const float4*)bufC, nsq);
    final_k<<<GB, 512, M * sizeof(float), stream>>>(bufC, nsq, dm, fc_w, fc_b,
                                                    outp, N, M);
    return;
  }

  // ---- v1 fallback ----
  float* h_cur  = (float*)d_ws;
  float* h_next = h_cur + BN;
  float* norms  = h_next + BN;
  const int threads = 256;
  init_k<<<(BN + threads - 1) / threads, threads, 0, stream>>>(x, h_cur, h_next,
                                                               norms, BN, NP * GB);
  int E4 = E / 4;
  int edgeBlocks = (E4 + threads - 1) / threads;
  dim3 ngrid((N + threads * 8 - 1) / (threads * 8), GB);
  for (int p = 0; p < NP; ++p) {
    edge_k<<<edgeBlocks, threads, 0, stream>>>(src, dst, ew, h_cur, h_next, E4, E);
    norm_k<<<ngrid, threads, 0, stream>>>(h_next, norms + p * GB, N);
    scale_k<<<ngrid, threads, 0, stream>>>(norms + p * GB, h_next, h_cur, N);
  }
  final_k<<<GB, 256, M * sizeof(float), stream>>>(h_cur, nullptr, dm, fc_w, fc_b,
                                                  (float*)d_out, N, M);
}

// Round 7
// 369.239 us; speedup vs baseline: 4.8235x; 4.8235x over previous
//
#include <hip/hip_runtime.h>
#include <hip/hip_fp16.h>
#include <math.h>

// Problem constants (fixed by setup_inputs): B=8 graphs, N=50000 nodes/graph,
// EPG=1e6 edges/graph, E=8e6, M=2048, num_passes=3.
#define GB    8
#define GN    50000
#define EPG   1000000
#define EDGES (GB*EPG)
#define NP    3

#define BW     4096           // dst-bucket width (floats) -> 16KB LDS accum
#define NBUCK  13             // ceil(50000/4096); last bucket width 848
#define NBINS  (GB*NBUCK)     // 104
#define CAP    89088          // recs capacity per bin (mean 81920, +26σ; mult of 4)
#define CPB    20             // chunk-blocks per bin -> 2080 accum blocks
#define STRIPE 2000           // edges per binning block (16KB LDS sort buffer)
#define NQ     (STRIPE/4)     // 500 quads
#define NBLKH  (EDGES/STRIPE) // 4000 binning blocks
#define BPG    (EPG/STRIPE)   // 500 blocks per graph
#define SRCMASK 0x7FFFFu      // src fits 19 bits (BN=400000 < 2^19)

// ============================ fast path ============================
// R6 datum: wall - kernel-sum = fixed ~62us harness overhead (dispatch-count
// independent); grid.sync costs ~200us each (abandoned). Remaining budget is
// pure kernel time; every record-traversal runs at ~2TB/s effective with all
// pipes idle => byte-wall (L3 fabric) or divergent-txn-wall. This round
// shrinks the record stream 8B -> 6B (SoA: u32 key + fp16 log1p-weight):
// tests the byte-wall without risking the txn-wall (fscatter stays
// coalesced via the proven R2 LDS-sort write-out).
// 1. z_k      : zero gcur/nsq + bufA/B/C
// 2. fscatter : 13-dst-bin rank+reserve, LDS-sort stripe, write per-bin runs
//               coalesced as SPLIT arrays: keys u32 (dst_loc<<19|src) +
//               wh fp16(log1pf(w)).
// 3. accum x3 : (bin,chunk) per 256-thr block; 4 recs per thread-step via
//               uint4 keys + uint2 halves, 2-deep; LDS accumulate; zero-skip
//               coalesced-atomic epilogue into pre-zeroed hout.
// 4. nsq_k    : per-graph sum-of-squares (norm telescopes to the end).
// 5. final_k  : mask/normalize/pool epilogue.

static __device__ __forceinline__ unsigned short f2h(float v) {
  union { __half h; unsigned short u; } cv;
  cv.h = __float2half(v);
  return cv.u;
}
static __device__ __forceinline__ float h2f(unsigned short s) {
  union { unsigned short u; __half h; } cv;
  cv.u = s;
  return __half2float(cv.h);
}

__global__ void z_k(int* __restrict__ gcur, float* __restrict__ nsq,
                    float4* __restrict__ a, float4* __restrict__ b,
                    float4* __restrict__ c) {
  int i = blockIdx.x * 256 + threadIdx.x;
  float4 z = {0.f, 0.f, 0.f, 0.f};
  if (i < (GB * GN) / 4) { a[i] = z; b[i] = z; c[i] = z; }
  if (blockIdx.x == 0) {
    if (threadIdx.x < NBINS) gcur[threadIdx.x] = 0;
    if (threadIdx.x < GB) nsq[threadIdx.x] = 0.f;
  }
}

// Fused bin+rank+reserve+LDS-sort+coalesced split-array scatter:
//  phase 1: per-edge rank within (block,bin) via LDS hist (ranks in regs)
//  phase 2: reserve per-bin global offset (13 atomics) + local prefix scan
//  phase 3a: re-read stripe (cache-resident), ds_write record to sorted slot
//  phase 3b: per-bin runs written coalesced: keys (u32) + weights (fp16).
// After the kernel, gcur[bin] == bin's record count (used by accum).
__global__ __launch_bounds__(256) void fscatter_k(
    const int* __restrict__ src, const int* __restrict__ dst,
    const float* __restrict__ ew, int* __restrict__ gcur,
    unsigned* __restrict__ keys, unsigned short* __restrict__ wh) {
  __shared__ int lh[NBUCK];     // per-bin count
  __shared__ int lsb[NBUCK];    // local sorted base (excl scan of lh)
  __shared__ int lbg[NBUCK];    // reserved global base
  __shared__ uint2 srt[STRIPE]; // 16KB sorted record buffer {key, f32 w bits}
  if (threadIdx.x < NBUCK) lh[threadIdx.x] = 0;
  __syncthreads();
  int blk = blockIdx.x;
  int s0 = blk * STRIPE;
  int g = blk / BPG;                  // stripe never crosses a graph
  int base = g * GN, gb = g * NBUCK;
  const int4* d4 = (const int4*)(dst + s0);
  const int4* s4 = (const int4*)(src + s0);
  const float4* w4 = (const float4*)(ew + s0);

  int rk[8];
#pragma unroll
  for (int u = 0; u < 2; ++u) {
    int q = threadIdx.x + 256 * u;
    if (q < NQ) {
      int4 d = d4[q];
      rk[4 * u + 0] = atomicAdd(&lh[(d.x - base) >> 12], 1);
      rk[4 * u + 1] = atomicAdd(&lh[(d.y - base) >> 12], 1);
      rk[4 * u + 2] = atomicAdd(&lh[(d.z - base) >> 12], 1);
      rk[4 * u + 3] = atomicAdd(&lh[(d.w - base) >> 12], 1);
    }
  }
  __syncthreads();
  if (threadIdx.x < NBUCK) {
    int c = lh[threadIdx.x];
    lbg[threadIdx.x] = c ? atomicAdd(&gcur[gb + threadIdx.x], c) : 0;
    int s = 0;
    for (int j = 0; j < threadIdx.x; ++j) s += lh[j];
    lsb[threadIdx.x] = s;
  }
  __syncthreads();
#pragma unroll
  for (int u = 0; u < 2; ++u) {
    int q = threadIdx.x + 256 * u;
    if (q < NQ) {
      int4 d = d4[q]; int4 s = s4[q]; float4 w = w4[q];
      int dv[4] = {d.x, d.y, d.z, d.w};
      int sv[4] = {s.x, s.y, s.z, s.w};
      float wv[4] = {w.x, w.y, w.z, w.w};
#pragma unroll
      for (int k = 0; k < 4; ++k) {
        int dl = dv[k] - base;
        int bin = dl >> 12;
        srt[lsb[bin] + rk[4 * u + k]] =
            make_uint2(((unsigned)(dl & (BW - 1)) << 19) | (unsigned)sv[k],
                       __float_as_uint(log1pf(wv[k])));
      }
    }
  }
  __syncthreads();
  for (int b = 0; b < NBUCK; ++b) {
    int cnt = lh[b];
    int lo = lsb[b];
    size_t bofs = (size_t)(gb + b) * CAP + lbg[b];
    unsigned* kd = keys + bofs;
    unsigned short* wd = wh + bofs;
    for (int i = threadIdx.x; i < cnt; i += 256) {
      uint2 r = srt[lo + i];
      kd[i] = r.x;
      wd[i] = f2h(__uint_as_float(r.y));
    }
  }
}

// One (bin, chunk) per 256-thread block: LDS-accumulate this bin's edges.
// 4 records per thread-step (uint4 keys + uint2 of 4 halves), 2-deep.
// Epilogue: zero-skip coalesced atomic add into hout (pre-zeroed).
__global__ __launch_bounds__(256) void accum_k(
    const unsigned* __restrict__ keys, const unsigned short* __restrict__ wh,
    const int* __restrict__ cnt, const float* __restrict__ hin,
    float* __restrict__ hout) {
  __shared__ float acc[BW];
  int c = blockIdx.x;               // chunk [0,CPB)
  int bin = blockIdx.y;             // [0,NBINS)
  float4 z = {0.f, 0.f, 0.f, 0.f};
  float4* a4 = (float4*)acc;
  for (int i = threadIdx.x; i < BW / 4; i += 256) a4[i] = z;
  int len = cnt[bin];
  int chunk = (((len + CPB - 1) / CPB) + 3) & ~3;   // multiple of 4
  int lo = c * chunk;
  int hi = lo + chunk;
  if (lo > len) lo = len;
  if (hi > len) hi = len;
  size_t bofs = (size_t)bin * CAP;
  __syncthreads();
  int rem = hi - lo;                // lo multiple of 4 (CAP, chunk mult 4)
  if (rem < 0) rem = 0;
  int n4 = rem >> 2;                // groups of 4 records
  const uint4* kp = (const uint4*)(keys + bofs + lo);
  const uint2* wp = (const uint2*)(wh + bofs + lo);
  int p = threadIdx.x;
  for (; p + 256 < n4; p += 512) {
    uint4 k0 = kp[p];
    uint4 k1 = kp[p + 256];
    uint2 w0 = wp[p];
    uint2 w1 = wp[p + 256];
    float v0 = hin[k0.x & SRCMASK] * h2f((unsigned short)(w0.x));
    float v1 = hin[k0.y & SRCMASK] * h2f((unsigned short)(w0.x >> 16));
    float v2 = hin[k0.z & SRCMASK] * h2f((unsigned short)(w0.y));
    float v3 = hin[k0.w & SRCMASK] * h2f((unsigned short)(w0.y >> 16));
    float v4 = hin[k1.x & SRCMASK] * h2f((unsigned short)(w1.x));
    float v5 = hin[k1.y & SRCMASK] * h2f((unsigned short)(w1.x >> 16));
    float v6 = hin[k1.z & SRCMASK] * h2f((unsigned short)(w1.y));
    float v7 = hin[k1.w & SRCMASK] * h2f((unsigned short)(w1.y >> 16));
    atomicAdd(&acc[k0.x >> 19], v0);
    atomicAdd(&acc[k0.y >> 19], v1);
    atomicAdd(&acc[k0.z >> 19], v2);
    atomicAdd(&acc[k0.w >> 19], v3);
    atomicAdd(&acc[k1.x >> 19], v4);
    atomicAdd(&acc[k1.y >> 19], v5);
    atomicAdd(&acc[k1.z >> 19], v6);
    atomicAdd(&acc[k1.w >> 19], v7);
  }
  if (p < n4) {
    uint4 k0 = kp[p];
    uint2 w0 = wp[p];
    atomicAdd(&acc[k0.x >> 19], hin[k0.x & SRCMASK] * h2f((unsigned short)(w0.x)));
    atomicAdd(&acc[k0.y >> 19], hin[k0.y & SRCMASK] * h2f((unsigned short)(w0.x >> 16)));
    atomicAdd(&acc[k0.z >> 19], hin[k0.z & SRCMASK] * h2f((unsigned short)(w0.y)));
    atomicAdd(&acc[k0.w >> 19], hin[k0.w & SRCMASK] * h2f((unsigned short)(w0.y >> 16)));
  }
  int tl = rem & 3;                 // 0..3 tail records
  if (threadIdx.x < tl) {
    int idx = lo + n4 * 4 + threadIdx.x;
    unsigned k = keys[bofs + idx];
    float v = hin[k & SRCMASK] * h2f(wh[bofs + idx]);
    atomicAdd(&acc[k >> 19], v);
  }
  __syncthreads();
  int g = bin / NBUCK, bucket = bin - g * NBUCK;
  int sw = GN - bucket * BW; if (sw > BW) sw = BW;   // 848 for bucket 12
  float* ho = hout + (size_t)g * GN + (size_t)bucket * BW;
  for (int i = threadIdx.x; i < sw; i += 256) {
    float v = acc[i];
    if (v != 0.f) unsafeAtomicAdd(&ho[i], v);
  }
}

// Per-graph sum of squares of h (device-wide, float4-vectorized).
__global__ void nsq_k(const float4* __restrict__ h4, float* __restrict__ nsq) {
  __shared__ float sm[GB];
  if (threadIdx.x < GB) sm[threadIdx.x] = 0.f;
  __syncthreads();
  int n4 = blockIdx.x * 256 + threadIdx.x;
  if (n4 < (GB * GN) / 4) {
    float4 t = h4[n4];
    int g = (n4 * 4) / GN;
    atomicAdd(&sm[g], t.x * t.x + t.y * t.y + t.z * t.z + t.w * t.w);
  }
  __syncthreads();
  if (threadIdx.x < GB && sm[threadIdx.x] != 0.f)
    unsafeAtomicAdd(&nsq[threadIdx.x], sm[threadIdx.x]);
}

// ============================ v1 fallback ============================

__global__ void init_k(const float* __restrict__ x, float* __restrict__ h_cur,
                       float* __restrict__ h_next, float* __restrict__ norms,
                       int BN, int n_norms) {
  int i = blockIdx.x * blockDim.x + threadIdx.x;
  int stride = gridDim.x * blockDim.x;
  for (int j = i; j < BN; j += stride) { h_cur[j] = x[j]; h_next[j] = 0.f; }
  if (i < n_norms) norms[i] = 0.f;
}

__global__ void edge_k(const int* __restrict__ src, const int* __restrict__ dst,
                       const float* __restrict__ ew, const float* __restrict__ h_in,
                       float* __restrict__ h_out, int E4, int E) {
  int i = blockIdx.x * blockDim.x + threadIdx.x;
  int stride = gridDim.x * blockDim.x;
  const int4* s4 = (const int4*)src;
  const int4* d4 = (const int4*)dst;
  const float4* w4 = (const float4*)ew;
  for (int j = i; j < E4; j += stride) {
    int4 s = s4[j]; int4 d = d4[j]; float4 w = w4[j];
    unsafeAtomicAdd(&h_out[d.x], h_in[s.x] * log1pf(w.x));
    unsafeAtomicAdd(&h_out[d.y], h_in[s.y] * log1pf(w.y));
    unsafeAtomicAdd(&h_out[d.z], h_in[s.z] * log1pf(w.z));
    unsafeAtomicAdd(&h_out[d.w], h_in[s.w] * log1pf(w.w));
  }
  for (int j = E4 * 4 + i; j < E; j += stride)
    unsafeAtomicAdd(&h_out[dst[j]], h_in[src[j]] * log1pf(ew[j]));
}

__global__ void norm_k(const float* __restrict__ h, float* __restrict__ norms, int N) {
  int g = blockIdx.y;
  const float* hg = h + (size_t)g * N;
  float s = 0.f;
  for (int j = blockIdx.x * blockDim.x + threadIdx.x; j < N; j += gridDim.x * blockDim.x) {
    float v = hg[j]; s += v * v;
  }
  __shared__ float sm[4];
  for (int o = 32; o > 0; o >>= 1) s += __shfl_down(s, o, 64);
  if ((threadIdx.x & 63) == 0) sm[threadIdx.x >> 6] = s;
  __syncthreads();
  if (threadIdx.x == 0) {
    float t = 0.f;
    for (int w = 0; w < (int)(blockDim.x >> 6); ++w) t += sm[w];
    unsafeAtomicAdd(&norms[g], t);
  }
}

__global__ void scale_k(const float* __restrict__ norms, float* __restrict__ h_next,
                        float* __restrict__ h_cur, int N) {
  int g = blockIdx.y;
  float inv = 1.0f / sqrtf(norms[g]);
  size_t off = (size_t)g * N;
  for (int j = blockIdx.x * blockDim.x + threadIdx.x; j < N; j += gridDim.x * blockDim.x) {
    h_cur[off + j] = h_next[off + j] * inv;
    h_next[off + j] = 0.f;
  }
}

// ============================ shared epilogue ============================
__device__ __forceinline__ float blk_red(float t, float* sm, int nw) {
  for (int o = 32; o > 0; o >>= 1) t += __shfl_down(t, o, 64);
  if ((threadIdx.x & 63) == 0) sm[threadIdx.x >> 6] = t;
  __syncthreads();
  float r = 0.f;
  for (int w = 0; w < nw; ++w) r += sm[w];
  __syncthreads();
  return r;
}

__global__ void final_k(const float* __restrict__ h, const float* __restrict__ nsq,
                        const int* __restrict__ dm,
                        const float* __restrict__ fc_w, const float* __restrict__ fc_b,
                        float* __restrict__ out, int N, int M) {
  extern __shared__ float v[];
  __shared__ float sm[16];
  int b = blockIdx.x;
  int nw = blockDim.x >> 6;
  float inv = nsq ? 1.0f / sqrtf(nsq[b]) : 1.0f;
  const float* hb = h + (size_t)b * N;
  for (int m = threadIdx.x; m < M; m += blockDim.x) v[m] = hb[dm[m]] * inv;
  __syncthreads();

  float cnt = 0.f, sum = 0.f;
  for (int m = threadIdx.x; m < M; m += blockDim.x) {
    float xv = v[m];
    if (xv != 0.f) { cnt += 1.f; sum += xv; }
  }
  float totalSum = blk_red(sum, sm, nw);
  float totalCnt = blk_red(cnt, sm, nw);
  float mean = totalCnt > 0.f ? totalSum / totalCnt : 0.f;

  float ssq = 0.f;
  for (int m = threadIdx.x; m < M; m += blockDim.x) {
    float xv = v[m];
    if (xv != 0.f) { float d = xv - mean; ssq += d * d; }
  }
  float totalSsq = blk_red(ssq, sm, nw);

  float denom = totalCnt - 1.f;
  if (denom < 1.f) denom = 1.f;
  float stdv = sqrtf(totalSsq / denom) + 1e-5f;

  float ps = 0.f;
  for (int m = threadIdx.x; m < M; m += blockDim.x) {
    float xv = v[m];
    if (xv != 0.f) ps += (xv - mean) / stdv;
  }
  float pooled = blk_red(ps, sm, nw) / (float)M;
  if (threadIdx.x == 0) {
    float o = pooled * fc_w[0] + fc_b[0];
    out[b] = o > 0.f ? o : 0.f;
  }
}

extern "C" void kernel_launch(void* const* d_in, const int* in_sizes, int n_in,
                              void* d_out, int out_size, void* d_ws, size_t ws_size,
                              hipStream_t stream) {
  const float* x    = (const float*)d_in[0];
  const float* ew   = (const float*)d_in[1];
  const int*   src  = (const int*)d_in[2];
  const int*   dst  = (const int*)d_in[3];
  const int*   dm   = (const int*)d_in[4];
  const float* fc_w = (const float*)d_in[5];
  const float* fc_b = (const float*)d_in[6];

  const int BN = in_sizes[0];   // 400000
  const int E  = in_sizes[1];   // 8000000
  const int M  = in_sizes[4];   // 2048
  const int N  = BN / GB;

  const bool shapes_ok = (BN == GB * GN) && (E == EDGES);

  // ---- layout (split arrays: keys u32 + weights fp16; REQ ~ 60.5 MB) ----
  const size_t keys_b = (size_t)NBINS * CAP * 4;   // 37,060,608
  const size_t wh_b   = (size_t)NBINS * CAP * 2;   // 18,530,304
  const size_t buf_b  = (size_t)BN * 4;            // 1,600,000
  const size_t misc_b = 4096;
  const size_t REQ = keys_b + wh_b + 3 * buf_b + misc_b;

  if (shapes_ok && ws_size >= REQ) {
    unsigned* keys       = (unsigned*)d_ws;
    unsigned short* wh   = (unsigned short*)((char*)d_ws + keys_b);
    float* bufA = (float*)((char*)d_ws + keys_b + wh_b);
    float* bufB = bufA + BN;
    float* bufC = bufB + BN;
    int*   gcur = (int*)(bufC + BN);               // [NBINS]; == counts after fscatter
    float* nsq  = (float*)(gcur + NBINS + 8);      // [GB]

    z_k<<<(BN / 4 + 255) / 256, 256, 0, stream>>>(gcur, nsq, (float4*)bufA,
                                                  (float4*)bufB, (float4*)bufC);
    fscatter_k<<<NBLKH, 256, 0, stream>>>(src, dst, ew, gcur, keys, wh);

    dim3 agrid(CPB, NBINS);
    accum_k<<<agrid, 256, 0, stream>>>(keys, wh, gcur, x, bufA);
    accum_k<<<agrid, 256, 0, stream>>>(keys, wh, gcur, bufA, bufB);
    accum_k<<<agrid, 256, 0, stream>>>(keys, wh, gcur, bufB, bufC);

    nsq_k<<<(BN / 4 + 255) / 256, 256, 0, stream>>>((const float4*)bufC, nsq);
    final_k<<<GB, 512, M * sizeof(float), stream>>>(bufC, nsq, dm, fc_w, fc_b,
                                                    (float*)d_out, N, M);
    return;
  }

  // ---- v1 fallback ----
  float* h_cur  = (float*)d_ws;
  float* h_next = h_cur + BN;
  float* norms  = h_next + BN;
  const int threads = 256;
  init_k<<<(BN + threads - 1) / threads, threads, 0, stream>>>(x, h_cur, h_next,
                                                               norms, BN, NP * GB);
  int E4 = E / 4;
  int edgeBlocks = (E4 + threads - 1) / threads;
  dim3 ngrid((N + threads * 8 - 1) / (threads * 8), GB);
  for (int p = 0; p < NP; ++p) {
    edge_k<<<edgeBlocks, threads, 0, stream>>>(src, dst, ew, h_cur, h_next, E4, E);
    norm_k<<<ngrid, threads, 0, stream>>>(h_next, norms + p * GB, N);
    scale_k<<<ngrid, threads, 0, stream>>>(norms + p * GB, h_next, h_cur, N);
  }
  final_k<<<GB, 256, M * sizeof(float), stream>>>(h_cur, nullptr, dm, fc_w, fc_b,
                                                  (float*)d_out, N, M);
}

// Round 8
// 338.566 us; speedup vs baseline: 5.2605x; 1.0906x over previous
//
#include <hip/hip_runtime.h>
#include <math.h>

// Problem constants (fixed by setup_inputs): B=8 graphs, N=50000 nodes/graph,
// EPG=1e6 edges/graph, E=8e6, M=2048, num_passes=3.
#define GB    8
#define GN    50000
#define EPG   1000000
#define EDGES (GB*EPG)
#define NP    3

#define BW     4096           // bucket width (floats) -> 16KB LDS in accum
#define NBUCK  13             // ceil(50000/4096); last bucket width 848
#define NBINS  (GB*NBUCK)     // 104
#define CAP    89088          // fixed recs capacity per bin (mean 81920, +26σ)
#define CPB    10             // chunk-blocks per bin -> 1040 accum blocks
#define STRIPE 4000           // edges per binning block
#define NQ     (STRIPE/4)     // 1000 quads
#define NBLKH  (EDGES/STRIPE) // 2000 binning blocks
#define BPG    (EPG/STRIPE)   // 250 blocks per graph
#define SRCMASK 0x7FFFFu      // src fits 19 bits (BN=400000 < 2^19)

// ============================ fast path ============================
// Champion R0 structure (334us measured) with ONE change: accum_k at 512
// threads -> 32 waves/CU (was 16). Occupancy is the only knob that ever
// moved accum (R5: 16->32 waves = 80->66us on the atomic-epilogue variant).
// Ledger of falsified alternatives: LDS-staged gather (R1), LDS-sort fscatter
// (R2/R7, +5us), batch-8 MLP (R3), random global atomics (R4, 50ns each),
// grid.sync fusion (R6, ~200us/sync), 6B records (R7, bytes don't matter).
// Model: all record kernels are divergent-lane-request bound (~2.2cyc/op/CU).

__global__ void z_k(int* __restrict__ gcur, float* __restrict__ nsq) {
  int t = threadIdx.x;
  if (t < NBINS) gcur[t] = 0;
  if (t < GB) nsq[t] = 0.f;
}

// Fused bin+rank+reserve+scatter (one kernel, no prefix scans):
//  phase 1: per-edge rank within (block,bin) via LDS hist (ranks in regs)
//  phase 2: reserve per-bin offset via gcur atomic (104/block)
//  phase 3: re-read stripe (L1-resident) and write records to the bin's
//           FIXED-CAPACITY slot: pos = bin*CAP + lb[bin] + rank.
// After the kernel, gcur[bin] == bin's record count (used by accum).
//   rec.x = (dst_local_in_bucket << 19) | src_global   rec.y = bits(log1pf(w))
__global__ __launch_bounds__(256) void fscatter_k(
    const int* __restrict__ src, const int* __restrict__ dst,
    const float* __restrict__ ew, int* __restrict__ gcur,
    uint2* __restrict__ recs) {
  __shared__ int lh[NBINS];
  __shared__ int lb[NBINS];
  if (threadIdx.x < NBINS) lh[threadIdx.x] = 0;
  __syncthreads();
  int blk = blockIdx.x;
  int s0 = blk * STRIPE;
  int g = blk / BPG;                  // stripe never crosses a graph
  int base = g * GN, gb = g * NBUCK;
  const int4* d4 = (const int4*)(dst + s0);
  const int4* s4 = (const int4*)(src + s0);
  const float4* w4 = (const float4*)(ew + s0);

  int rk[16];
#pragma unroll
  for (int u = 0; u < 4; ++u) {
    int q = threadIdx.x + 256 * u;
    if (q < NQ) {
      int4 d = d4[q];
      rk[4 * u + 0] = atomicAdd(&lh[gb + ((d.x - base) >> 12)], 1);
      rk[4 * u + 1] = atomicAdd(&lh[gb + ((d.y - base) >> 12)], 1);
      rk[4 * u + 2] = atomicAdd(&lh[gb + ((d.z - base) >> 12)], 1);
      rk[4 * u + 3] = atomicAdd(&lh[gb + ((d.w - base) >> 12)], 1);
    }
  }
  __syncthreads();
  if (threadIdx.x < NBINS) {
    int c = lh[threadIdx.x];
    lb[threadIdx.x] = c ? atomicAdd(&gcur[threadIdx.x], c) : 0;
  }
  __syncthreads();
#pragma unroll
  for (int u = 0; u < 4; ++u) {
    int q = threadIdx.x + 256 * u;
    if (q < NQ) {
      int4 d = d4[q]; int4 s = s4[q]; float4 w = w4[q];
      int dv[4] = {d.x, d.y, d.z, d.w};
      int sv[4] = {s.x, s.y, s.z, s.w};
      float wv[4] = {w.x, w.y, w.z, w.w};
#pragma unroll
      for (int k = 0; k < 4; ++k) {
        int dl = dv[k] - base;
        int bin = gb + (dl >> 12);
        int r = dl & (BW - 1);
        size_t pos = (size_t)bin * CAP + lb[bin] + rk[4 * u + k];
        recs[pos] = make_uint2(((unsigned)r << 19) | (unsigned)sv[k],
                               __float_as_uint(log1pf(wv[k])));
      }
    }
  }
}

// One (bin, chunk) per 512-thread block: LDS-accumulate this bin's edges;
// 2x uint4/iter. 1040 blocks -> 4 blocks/CU -> 32 waves/CU (was 16 at 256thr).
// Bin's records live at recs[bin*CAP .. bin*CAP+cnt[bin]) -- lo always even.
// Normalization telescoped into the epilogue.
__global__ __launch_bounds__(512) void accum_k(
    const uint2* __restrict__ recs, const int* __restrict__ cnt,
    const float* __restrict__ hin, float* __restrict__ partials) {
  __shared__ float acc[BW];
  int c = blockIdx.x;               // chunk [0,CPB)
  int bin = blockIdx.y;             // [0,NBINS)
  float4 z = {0.f, 0.f, 0.f, 0.f};
  float4* a4 = (float4*)acc;
  for (int i = threadIdx.x; i < BW / 4; i += 512) a4[i] = z;
  int len = cnt[bin];
  int chunk = ((len + CPB - 1) / CPB + 1) & ~1;   // even chunk
  int lo = c * chunk;
  int hi = lo + chunk;
  if (lo > len) lo = len;
  if (hi > len) hi = len;
  const uint2* rb = recs + (size_t)bin * CAP;
  __syncthreads();
  int rem = hi - lo;                // lo even (CAP even, chunk even)
  if (rem < 0) rem = 0;
  int np = rem >> 1;                // uint4 count (2 recs each)
  const uint4* rp = (const uint4*)(rb + lo);
  int p = threadIdx.x;
  for (; p + 512 < np; p += 1024) {
    uint4 r0 = rp[p];
    uint4 r1 = rp[p + 512];
    float a0 = hin[r0.x & SRCMASK] * __uint_as_float(r0.y);
    float a1 = hin[r0.z & SRCMASK] * __uint_as_float(r0.w);
    float a2 = hin[r1.x & SRCMASK] * __uint_as_float(r1.y);
    float a3 = hin[r1.z & SRCMASK] * __uint_as_float(r1.w);
    atomicAdd(&acc[r0.x >> 19], a0);
    atomicAdd(&acc[r0.z >> 19], a1);
    atomicAdd(&acc[r1.x >> 19], a2);
    atomicAdd(&acc[r1.z >> 19], a3);
  }
  if (p < np) {
    uint4 r0 = rp[p];
    atomicAdd(&acc[r0.x >> 19], hin[r0.x & SRCMASK] * __uint_as_float(r0.y));
    atomicAdd(&acc[r0.z >> 19], hin[r0.z & SRCMASK] * __uint_as_float(r0.w));
  }
  if ((rem & 1) && threadIdx.x == 0) {
    uint2 a = rb[hi - 1];
    atomicAdd(&acc[a.x >> 19], hin[a.x & SRCMASK] * __uint_as_float(a.y));
  }
  __syncthreads();
  float4* po = (float4*)(partials + ((size_t)bin * CPB + c) * BW);
  for (int i = threadIdx.x; i < BW / 4; i += 512) po[i] = a4[i];
}

// Sum CPB chunk-partials per node, float4-vectorized; optional fused ssq.
__global__ void reduce_k(const float* __restrict__ partials,
                         float* __restrict__ hout, float* __restrict__ nsq) {
  __shared__ float sm[GB];
  if (threadIdx.x < GB) sm[threadIdx.x] = 0.f;
  __syncthreads();
  int n4 = blockIdx.x * 256 + threadIdx.x;
  if (n4 < (GB * GN) / 4) {
    int n = n4 * 4;
    int g = n / GN;
    int dl = n - g * GN;
    int bucket = dl >> 12;
    int slot = dl & (BW - 1);
    const float4* p = (const float4*)(partials +
        ((size_t)(g * NBUCK + bucket) * CPB) * BW + slot);
    float4 s = {0.f, 0.f, 0.f, 0.f};
#pragma unroll
    for (int c = 0; c < CPB; ++c) {
      float4 t = p[c * (BW / 4)];
      s.x += t.x; s.y += t.y; s.z += t.z; s.w += t.w;
    }
    ((float4*)hout)[n4] = s;
    if (nsq) atomicAdd(&sm[g], s.x * s.x + s.y * s.y + s.z * s.z + s.w * s.w);
  }
  __syncthreads();
  if (nsq && threadIdx.x < GB && sm[threadIdx.x] != 0.f)
    unsafeAtomicAdd(&nsq[threadIdx.x], sm[threadIdx.x]);
}

// ============================ v1 fallback ============================

__global__ void init_k(const float* __restrict__ x, float* __restrict__ h_cur,
                       float* __restrict__ h_next, float* __restrict__ norms,
                       int BN, int n_norms) {
  int i = blockIdx.x * blockDim.x + threadIdx.x;
  int stride = gridDim.x * blockDim.x;
  for (int j = i; j < BN; j += stride) { h_cur[j] = x[j]; h_next[j] = 0.f; }
  if (i < n_norms) norms[i] = 0.f;
}

__global__ void edge_k(const int* __restrict__ src, const int* __restrict__ dst,
                       const float* __restrict__ ew, const float* __restrict__ h_in,
                       float* __restrict__ h_out, int E4, int E) {
  int i = blockIdx.x * blockDim.x + threadIdx.x;
  int stride = gridDim.x * blockDim.x;
  const int4* s4 = (const int4*)src;
  const int4* d4 = (const int4*)dst;
  const float4* w4 = (const float4*)ew;
  for (int j = i; j < E4; j += stride) {
    int4 s = s4[j]; int4 d = d4[j]; float4 w = w4[j];
    unsafeAtomicAdd(&h_out[d.x], h_in[s.x] * log1pf(w.x));
    unsafeAtomicAdd(&h_out[d.y], h_in[s.y] * log1pf(w.y));
    unsafeAtomicAdd(&h_out[d.z], h_in[s.z] * log1pf(w.z));
    unsafeAtomicAdd(&h_out[d.w], h_in[s.w] * log1pf(w.w));
  }
  for (int j = E4 * 4 + i; j < E; j += stride)
    unsafeAtomicAdd(&h_out[dst[j]], h_in[src[j]] * log1pf(ew[j]));
}

__global__ void norm_k(const float* __restrict__ h, float* __restrict__ norms, int N) {
  int g = blockIdx.y;
  const float* hg = h + (size_t)g * N;
  float s = 0.f;
  for (int j = blockIdx.x * blockDim.x + threadIdx.x; j < N; j += gridDim.x * blockDim.x) {
    float v = hg[j]; s += v * v;
  }
  __shared__ float sm[4];
  for (int o = 32; o > 0; o >>= 1) s += __shfl_down(s, o, 64);
  if ((threadIdx.x & 63) == 0) sm[threadIdx.x >> 6] = s;
  __syncthreads();
  if (threadIdx.x == 0) {
    float t = 0.f;
    for (int w = 0; w < (int)(blockDim.x >> 6); ++w) t += sm[w];
    unsafeAtomicAdd(&norms[g], t);
  }
}

__global__ void scale_k(const float* __restrict__ norms, float* __restrict__ h_next,
                        float* __restrict__ h_cur, int N) {
  int g = blockIdx.y;
  float inv = 1.0f / sqrtf(norms[g]);
  size_t off = (size_t)g * N;
  for (int j = blockIdx.x * blockDim.x + threadIdx.x; j < N; j += gridDim.x * blockDim.x) {
    h_cur[off + j] = h_next[off + j] * inv;
    h_next[off + j] = 0.f;
  }
}

// ============================ shared epilogue ============================
__device__ __forceinline__ float blk_red(float t, float* sm, int nw) {
  for (int o = 32; o > 0; o >>= 1) t += __shfl_down(t, o, 64);
  if ((threadIdx.x & 63) == 0) sm[threadIdx.x >> 6] = t;
  __syncthreads();
  float r = 0.f;
  for (int w = 0; w < nw; ++w) r += sm[w];
  __syncthreads();
  return r;
}

__global__ void final_k(const float* __restrict__ h, const float* __restrict__ nsq,
                        const int* __restrict__ dm,
                        const float* __restrict__ fc_w, const float* __restrict__ fc_b,
                        float* __restrict__ out, int N, int M) {
  extern __shared__ float v[];
  __shared__ float sm[16];
  int b = blockIdx.x;
  int nw = blockDim.x >> 6;
  float inv = nsq ? 1.0f / sqrtf(nsq[b]) : 1.0f;
  const float* hb = h + (size_t)b * N;
  for (int m = threadIdx.x; m < M; m += blockDim.x) v[m] = hb[dm[m]] * inv;
  __syncthreads();

  float cnt = 0.f, sum = 0.f;
  for (int m = threadIdx.x; m < M; m += blockDim.x) {
    float xv = v[m];
    if (xv != 0.f) { cnt += 1.f; sum += xv; }
  }
  float totalSum = blk_red(sum, sm, nw);
  float totalCnt = blk_red(cnt, sm, nw);
  float mean = totalCnt > 0.f ? totalSum / totalCnt : 0.f;

  float ssq = 0.f;
  for (int m = threadIdx.x; m < M; m += blockDim.x) {
    float xv = v[m];
    if (xv != 0.f) { float d = xv - mean; ssq += d * d; }
  }
  float totalSsq = blk_red(ssq, sm, nw);

  float denom = totalCnt - 1.f;
  if (denom < 1.f) denom = 1.f;
  float stdv = sqrtf(totalSsq / denom) + 1e-5f;

  float ps = 0.f;
  for (int m = threadIdx.x; m < M; m += blockDim.x) {
    float xv = v[m];
    if (xv != 0.f) ps += (xv - mean) / stdv;
  }
  float pooled = blk_red(ps, sm, nw) / (float)M;
  if (threadIdx.x == 0) {
    float o = pooled * fc_w[0] + fc_b[0];
    out[b] = o > 0.f ? o : 0.f;
  }
}

extern "C" void kernel_launch(void* const* d_in, const int* in_sizes, int n_in,
                              void* d_out, int out_size, void* d_ws, size_t ws_size,
                              hipStream_t stream) {
  const float* x    = (const float*)d_in[0];
  const float* ew   = (const float*)d_in[1];
  const int*   src  = (const int*)d_in[2];
  const int*   dst  = (const int*)d_in[3];
  const int*   dm   = (const int*)d_in[4];
  const float* fc_w = (const float*)d_in[5];
  const float* fc_b = (const float*)d_in[6];

  const int BN = in_sizes[0];   // 400000
  const int E  = in_sizes[1];   // 8000000
  const int M  = in_sizes[4];   // 2048
  const int N  = BN / GB;

  const bool shapes_ok = (BN == GB * GN) && (E == EDGES);

  // ---- layout (fixed-capacity recs; REQ = 94,364,672 <= verified floor) ----
  const size_t recs_b  = (size_t)NBINS * CAP * 8;    // 74,121,216
  const size_t part_b  = (size_t)NBINS * CPB * BW * 4; // 17,039,360
  const size_t buf_b   = (size_t)BN * 4;             // 1,600,000
  const size_t misc_b  = 4096;
  const size_t REQ = recs_b + part_b + 2 * buf_b + misc_b;

  if (shapes_ok && ws_size >= REQ) {
    uint2* recs     = (uint2*)d_ws;
    float* partials = (float*)((char*)d_ws + recs_b);
    float* bufA     = (float*)((char*)partials + part_b);
    float* bufB     = (float*)((char*)bufA + buf_b);
    char*  misc     = (char*)bufB + buf_b;
    int*   gcur     = (int*)misc;                    // [NBINS]; == counts after fscatter
    float* nsq      = (float*)(gcur + NBINS + 8);    // [GB]

    z_k<<<1, 128, 0, stream>>>(gcur, nsq);
    fscatter_k<<<NBLKH, 256, 0, stream>>>(src, dst, ew, gcur, recs);

    int rgrid = (BN / 4 + 255) / 256;   // 391
    dim3 agrid(CPB, NBINS);
    accum_k<<<agrid, 512, 0, stream>>>(recs, gcur, x, partials);
    reduce_k<<<rgrid, 256, 0, stream>>>(partials, bufA, nullptr);
    accum_k<<<agrid, 512, 0, stream>>>(recs, gcur, bufA, partials);
    reduce_k<<<rgrid, 256, 0, stream>>>(partials, bufB, nullptr);
    accum_k<<<agrid, 512, 0, stream>>>(recs, gcur, bufB, partials);
    reduce_k<<<rgrid, 256, 0, stream>>>(partials, bufA, nsq);     // fused final ssq

    final_k<<<GB, 512, M * sizeof(float), stream>>>(bufA, nsq, dm, fc_w, fc_b,
                                                    (float*)d_out, N, M);
    return;
  }

  // ---- v1 fallback ----
  float* h_cur  = (float*)d_ws;
  float* h_next = h_cur + BN;
  float* norms  = h_next + BN;
  const int threads = 256;
  init_k<<<(BN + threads - 1) / threads, threads, 0, stream>>>(x, h_cur, h_next,
                                                               norms, BN, NP * GB);
  int E4 = E / 4;
  int edgeBlocks = (E4 + threads - 1) / threads;
  dim3 ngrid((N + threads * 8 - 1) / (threads * 8), GB);
  for (int p = 0; p < NP; ++p) {
    edge_k<<<edgeBlocks, threads, 0, stream>>>(src, dst, ew, h_cur, h_next, E4, E);
    norm_k<<<ngrid, threads, 0, stream>>>(h_next, norms + p * GB, N);
    scale_k<<<ngrid, threads, 0, stream>>>(norms + p * GB, h_next, h_cur, N);
  }
  final_k<<<GB, 256, M * sizeof(float), stream>>>(h_cur, nullptr, dm, fc_w, fc_b,
                                                  (float*)d_out, N, M);
}